// Round 1
// 1140.759 us; speedup vs baseline: 1.1417x; 1.1417x over previous
//
#include <hip/hip_runtime.h>
#include <hip/hip_bf16.h>
#include <cstdint>
#include <cstddef>

// MultiGateMixExperts: fp16 MFMA GEMMs, frag-major layout.
// Frag-major layout: frag(tile16 t, kchunk32 c) = 1KB at ((t*32+c)*64+lane)*16B;
// lane l holds M[row=t*16+(l&15)][k=c*32+(l>>4)*8 .. +7] (fp16).
// R6: replace direct global->VGPR fragment streaming (latency-bound, MfmaUtil
// 26%, 2 blocks/CU) with m97-style double-buffered LDS staging:
//  - each 1KB frag = ONE global_load_lds_dwordx4 (wave-uniform linear LDS dest,
//    per-lane global src) -> async, no VGPR round-trip, each frag fetched once
//    per block (was 2x: wm/wn wave pairs duplicated loads).
//  - 2 barriers per 32-k chunk; __syncthreads drains vmcnt so staged chunk is
//    ready and buffer reuse is safe.
//  - depth-2 reg prefetch buffers (64 VGPRs) dropped -> 3-4 blocks/CU resident.
// Keeps: XCD-windowed remap, frag layout, fused stage-3 f epilogue.
// h1 = sigmoid(x@W1[e]+b1); h2 = relu(h1@W2[e]+b2);
// f = (h2@W2[e]+b2).Wo[e] fused into stage-3 epilogue (atomicAdd over n-blocks)
// out_i = softmax(x@Wg_i+bg_i) . (f+bo)

using half8   = __attribute__((ext_vector_type(8))) _Float16;
using floatx4 = __attribute__((ext_vector_type(4))) float;

// ---------------------------------------------------------------- GEMM ------
// ACT: 0=sigmoid, 1=relu (writes C in frag layout), 2=f-fused (no C store).
// Block 128x128, 4 waves (2x2), wave tile 64x64 (4x4 of 16x16x32).
template<int ACT>
__global__ __launch_bounds__(256, 3)
void gemm_kernel(const _Float16* __restrict__ A, const _Float16* __restrict__ Bt,
                 const float* __restrict__ bias, _Float16* __restrict__ C,
                 size_t a_estride,
                 const float* __restrict__ Wo, float* __restrict__ f, int e0)
{
    // 2 x 16KB k-chunk buffers: frag f (0..7 = A m-tiles, 8..15 = B n-tiles),
    // 512 halves each, lane-linear. Reused as epilogue repack tile.
    __shared__ __align__(16) _Float16 sbuf[2][16 * 512];

    const int tid  = threadIdx.x;
    const int lane = tid & 63;
    const int w    = tid >> 6;      // wave 0..3
    const int wm   = w & 1;
    const int wn   = w >> 1;

    // --- XCD-aware windowed remap (gridDim = {8, 64, g}) ---
    const int g    = gridDim.z;
    const int flat = blockIdx.x + (blockIdx.y << 3) + (blockIdx.z << 9);
    const int xcd  = flat & 7;
    int s = flat >> 3;
    int le, mb_base;
    if (g <= 8) {
        const int p = 8 / g;            // XCDs per expert
        le = xcd / p;
        mb_base = (xcd % p) * (64 / p);
    } else {                            // g == 16
        le = (xcd << 1) | (s >> 9);
        s &= 511;
        mb_base = 0;
    }
    const int nb = (s >> 2) & 7;
    const int mb = mb_base + (s >> 5) * 4 + (s & 3);
    const int m0 = mb * 128;
    const int n0 = nb * 128;

    const _Float16* Ae = A   + (size_t)le * a_estride;
    const _Float16* Be = Bt  + (size_t)le * (1024ull * 1024ull);
    const float*    be = bias + (size_t)le * 1024ull;
    _Float16*       Ce = C   + (size_t)le * (8192ull * 1024ull);

    const int mtb_blk = m0 >> 4;          // block's first A m-tile (8 total)
    const int ntb_blk = n0 >> 4;          // block's first B n-tile (8 total)
    const int mtb = mtb_blk + wm * 4;     // wave's first m-tile

    // staging: wave w owns frags w*4 .. w*4+3; per-lane global src (+lane*16B),
    // advanced 512 halves per staged chunk.
    const _Float16* gs[4];
#pragma unroll
    for (int u = 0; u < 4; ++u) {
        const int fidx = w * 4 + u;
        gs[u] = (fidx < 8)
            ? (Ae + (size_t)(mtb_blk + fidx) * (32 * 512) + lane * 8)
            : (Be + (size_t)(ntb_blk + (fidx - 8)) * (32 * 512) + lane * 8);
    }

    floatx4 acc[4][4];
#pragma unroll
    for (int i = 0; i < 4; ++i)
#pragma unroll
        for (int j = 0; j < 4; ++j) { floatx4 z = {0.f, 0.f, 0.f, 0.f}; acc[i][j] = z; }

    auto STAGE = [&](_Float16* buf) {
#pragma unroll
        for (int u = 0; u < 4; ++u) {
            __builtin_amdgcn_global_load_lds(
                (const __attribute__((address_space(1))) void*)gs[u],
                (__attribute__((address_space(3))) void*)(buf + (w * 4 + u) * 512),
                16, 0, 0);
            gs[u] += 512;
        }
    };
    auto COMPUTE = [&](const _Float16* buf) {
        half8 a[4], b[4];
#pragma unroll
        for (int i = 0; i < 4; ++i)
            a[i] = *(const half8*)(buf + (wm * 4 + i) * 512 + lane * 8);
#pragma unroll
        for (int j = 0; j < 4; ++j)
            b[j] = *(const half8*)(buf + 4096 + (wn * 4 + j) * 512 + lane * 8);
#pragma unroll
        for (int i = 0; i < 4; ++i)
#pragma unroll
            for (int j = 0; j < 4; ++j)
                acc[i][j] = __builtin_amdgcn_mfma_f32_16x16x32_f16(a[i], b[j], acc[i][j], 0, 0, 0);
    };

    // K = 1024 -> 32 chunks of 32. Double-buffered, 1 barrier per chunk.
    STAGE(sbuf[0]);                       // chunk 0
    __syncthreads();
#pragma unroll 1
    for (int c = 0; c < 30; c += 2) {
        STAGE(sbuf[1]);                   // chunk c+1
        COMPUTE(sbuf[0]);                 // chunk c
        __syncthreads();
        STAGE(sbuf[0]);                   // chunk c+2
        COMPUTE(sbuf[1]);                 // chunk c+1
        __syncthreads();
    }
    STAGE(sbuf[1]);                       // chunk 31
    COMPUTE(sbuf[0]);                     // chunk 30
    __syncthreads();
    COMPUTE(sbuf[1]);                     // chunk 31

    // ----- epilogue; C/D layout: col=lane&15, row=(lane>>4)*4+r -----
    const int q   = lane >> 4;
    const int l15 = lane & 15;
    float bj[4];
#pragma unroll
    for (int j = 0; j < 4; ++j) bj[j] = be[n0 + wn * 64 + j * 16 + l15];

    if (ACT == 2) {
        // f[m, e0+le] += sum_n (acc + b2[n]) * Wo[e0+le, n]
        const float* we = Wo + (size_t)(e0 + le) * 1024;
        float wj[4];
#pragma unroll
        for (int j = 0; j < 4; ++j) wj[j] = we[n0 + wn * 64 + j * 16 + l15];
#pragma unroll
        for (int i = 0; i < 4; ++i) {
            const int mbase = m0 + wm * 64 + i * 16 + q * 4;
#pragma unroll
            for (int r = 0; r < 4; ++r) {
                float sacc = 0.f;
#pragma unroll
                for (int j = 0; j < 4; ++j) sacc += (acc[i][j][r] + bj[j]) * wj[j];
#pragma unroll
                for (int m = 1; m < 16; m <<= 1) sacc += __shfl_xor(sacc, m, 64);
                if (l15 == 0) atomicAdd(&f[(size_t)(mbase + r) * 16 + (e0 + le)], sacc);
            }
        }
    } else {
        // per-wave LDS repack reusing the staging buffer (2 passes of 32 rows;
        // no cross-wave access after the barrier -> no further barriers)
        __syncthreads();                  // all waves done reading sbuf
        _Float16* T = &sbuf[0][0] + w * (32 * 72);
        const int kcg0 = ((n0 + wn * 64) >> 5);
#pragma unroll
        for (int p = 0; p < 2; ++p) {
#pragma unroll
            for (int i2 = 0; i2 < 2; ++i2) {
                const int i = p * 2 + i2;
#pragma unroll
                for (int r = 0; r < 4; ++r) {
                    const int row = i2 * 16 + q * 4 + r;
#pragma unroll
                    for (int j = 0; j < 4; ++j) {
                        float v = acc[i][j][r] + bj[j];
                        if (ACT == 0) v = 1.0f / (1.0f + __expf(-v));
                        else          v = fmaxf(v, 0.0f);
                        T[row * 72 + j * 16 + l15] = (_Float16)v;
                    }
                }
            }
#pragma unroll
            for (int i2 = 0; i2 < 2; ++i2) {
                const int i = p * 2 + i2;
                const int mt = mtb + i;
#pragma unroll
                for (int kci = 0; kci < 2; ++kci) {
                    half8 v = *(const half8*)(T + (i2 * 16 + l15) * 72 + kci * 32 + q * 8);
                    *(half8*)(Ce + ((size_t)mt * 32 + kcg0 + kci) * 512 + lane * 8) = v;
                }
            }
        }
    }
}

// --------------------------------------- cast x to fp16 frag layout ---------
__global__ __launch_bounds__(256)
void castx_kernel(const float* __restrict__ x, _Float16* __restrict__ xb)
{
    __shared__ _Float16 tile[64 * 72];   // [m-local][k-local]
    const int k0 = blockIdx.x * 64;
    const int m0 = blockIdx.y * 64;
    const int tid = threadIdx.x;
    const int col4 = (tid & 15) * 4;
    const int rb   = tid >> 4;           // 0..15
#pragma unroll
    for (int p = 0; p < 4; ++p) {
        const int row = rb + p * 16;
        float4 a = *(const float4*)(x + (size_t)(m0 + row) * 1024 + k0 + col4);
        _Float16* d = tile + row * 72 + col4;
        d[0] = (_Float16)a.x; d[1] = (_Float16)a.y; d[2] = (_Float16)a.z; d[3] = (_Float16)a.w;
    }
    __syncthreads();
    const int lane = tid & 63, w = tid >> 6;
    const int l15 = lane & 15, q = lane >> 4;
#pragma unroll
    for (int ff = 0; ff < 2; ++ff) {
        const int fidx = w * 2 + ff;
        const int mi = fidx >> 1, kci = fidx & 1;
        half8 v = *(const half8*)(tile + (mi * 16 + l15) * 72 + kci * 32 + q * 8);
        const size_t mt = (m0 >> 4) + mi, kc = (k0 >> 5) + kci;
        *(half8*)(xb + (mt * 32 + kc) * 512 + lane * 8) = v;
    }
}

// ------------------- W1/W2 [d][h] fp32 -> frag-major fp16 (n=h, k=d) --------
__global__ __launch_bounds__(256)
void wtr_kernel(const float* __restrict__ W1, const float* __restrict__ W2,
                _Float16* __restrict__ W1F, _Float16* __restrict__ W2F)
{
    __shared__ _Float16 tile[64 * 73];   // [k-local][n-local], pad 73
    const int z = blockIdx.z;
    const float* src = (z < 16) ? (W1 + (size_t)z * 1048576ull) : (W2 + (size_t)(z - 16) * 1048576ull);
    _Float16*    dst = (z < 16) ? (W1F + (size_t)z * 1048576ull) : (W2F + (size_t)(z - 16) * 1048576ull);
    const int n0 = blockIdx.x * 64;
    const int k0 = blockIdx.y * 64;
    const int tid = threadIdx.x;
    const int col = tid & 63;
    const int rb  = tid >> 6;            // 0..3
#pragma unroll
    for (int p = 0; p < 16; ++p) {
        const int row = rb * 16 + p;
        tile[row * 73 + col] = (_Float16)src[(size_t)(k0 + row) * 1024 + n0 + col];
    }
    __syncthreads();
    const int lane = tid & 63, w = tid >> 6;
    const int l15 = lane & 15, q = lane >> 4;
#pragma unroll
    for (int ff = 0; ff < 2; ++ff) {
        const int fidx = w * 2 + ff;
        const int nti = fidx >> 1, kci = fidx & 1;
        half8 v;
#pragma unroll
        for (int jj = 0; jj < 8; ++jj)
            v[jj] = tile[(kci * 32 + q * 8 + jj) * 73 + nti * 16 + l15];
        const size_t nt = (n0 >> 4) + nti, kc = (k0 >> 5) + kci;
        *(half8*)(dst + (nt * 32 + kc) * 512 + lane * 8) = v;
    }
}

// ---------------------------------------------------- zero f ----------------
__global__ __launch_bounds__(256)
void zerof_kernel(float* __restrict__ f)
{
    const size_t i = ((size_t)blockIdx.x * 256 + threadIdx.x) * 4;
    float4 z = {0.f, 0.f, 0.f, 0.f};
    *(float4*)(f + i) = z;
}

// ------------------ gates (fp32, full precision) + softmax + combine --------
__global__ __launch_bounds__(256)
void final_kernel(const float* __restrict__ x,
                  const float* __restrict__ Wg1, const float* __restrict__ bg1,
                  const float* __restrict__ Wg2, const float* __restrict__ bg2,
                  const float* __restrict__ f, const float* __restrict__ bo,
                  float* __restrict__ out)
{
    const int lane = threadIdx.x & 63;
    const int w    = threadIdx.x >> 6;
    const int b    = blockIdx.x * 4 + w;
    const float* xr = x + (size_t)b * 1024;
    float gp1[16], gp2[16];
#pragma unroll
    for (int e = 0; e < 16; ++e) { gp1[e] = 0.f; gp2[e] = 0.f; }
    for (int t = 0; t < 16; ++t) {
        const int d = t * 64 + lane;
        const float xv = xr[d];
        const float* w1r = Wg1 + (size_t)d * 16;
        const float* w2r = Wg2 + (size_t)d * 16;
#pragma unroll
        for (int e = 0; e < 16; ++e) { gp1[e] += xv * w1r[e]; gp2[e] += xv * w2r[e]; }
    }
#pragma unroll
    for (int e = 0; e < 16; ++e) {
#pragma unroll
        for (int m = 1; m < 64; m <<= 1) {
            gp1[e] += __shfl_xor(gp1[e], m, 64);
            gp2[e] += __shfl_xor(gp2[e], m, 64);
        }
    }
    float a1[16], a2[16], m1 = -1e30f, m2 = -1e30f;
#pragma unroll
    for (int e = 0; e < 16; ++e) {
        a1[e] = gp1[e] + bg1[e]; m1 = fmaxf(m1, a1[e]);
        a2[e] = gp2[e] + bg2[e]; m2 = fmaxf(m2, a2[e]);
    }
    float s1 = 0.f, s2 = 0.f;
#pragma unroll
    for (int e = 0; e < 16; ++e) {
        a1[e] = __expf(a1[e] - m1); s1 += a1[e];
        a2[e] = __expf(a2[e] - m2); s2 += a2[e];
    }
    float o1 = 0.f, o2 = 0.f;
    const float* fb = f + (size_t)b * 16;
#pragma unroll
    for (int e = 0; e < 16; ++e) {
        const float fe = fb[e] + bo[e];
        o1 += a1[e] * fe; o2 += a2[e] * fe;
    }
    if (lane == 0) { out[b] = o1 / s1; out[8192 + b] = o2 / s2; }
}

// ----------------------------------------------------------------------------
extern "C" void kernel_launch(void* const* d_in, const int* in_sizes, int n_in,
                              void* d_out, int out_size, void* d_ws, size_t ws_size,
                              hipStream_t stream)
{
    const float* x   = (const float*)d_in[0];
    const float* W1  = (const float*)d_in[1];
    const float* b1  = (const float*)d_in[2];
    const float* W2  = (const float*)d_in[3];
    const float* b2  = (const float*)d_in[4];
    const float* Wo  = (const float*)d_in[5];
    const float* bo  = (const float*)d_in[6];
    const float* Wg1 = (const float*)d_in[7];
    const float* bg1 = (const float*)d_in[8];
    const float* Wg2 = (const float*)d_in[9];
    const float* bg2 = (const float*)d_in[10];
    float* out = (float*)d_out;

    char* ws = (char*)d_ws;
    _Float16* xb  = (_Float16*)(ws);                         // 16 MB (frag)
    _Float16* W1F = (_Float16*)(ws + 16777216ull);           // 32 MB (frag)
    _Float16* W2F = (_Float16*)(ws + 50331648ull);           // 32 MB (frag)
    float*    f   = (float*)   (ws + 83886080ull);           // 0.5 MB
    char* hbase = ws + 84410368ull;

    int g = 1;
    const int cands[4] = {16, 8, 4, 2};
    for (int ci = 0; ci < 4; ++ci) {
        const size_t need = 84410368ull + 2ull * cands[ci] * 16777216ull;
        if (need <= ws_size) { g = cands[ci]; break; }
    }
    _Float16* h0 = (_Float16*)hbase;
    _Float16* h1 = (_Float16*)(hbase + (size_t)g * 16777216ull);

    castx_kernel<<<dim3(16, 128), 256, 0, stream>>>(x, xb);
    wtr_kernel<<<dim3(16, 16, 32), 256, 0, stream>>>(W1, W2, W1F, W2F);
    zerof_kernel<<<128, 256, 0, stream>>>(f);

    for (int e0 = 0; e0 < 16; e0 += g) {
        gemm_kernel<0><<<dim3(8, 64, g), 256, 0, stream>>>(
            xb, W1F + (size_t)e0 * 1048576ull, b1 + (size_t)e0 * 1024, h0, 0,
            nullptr, nullptr, 0);
        gemm_kernel<1><<<dim3(8, 64, g), 256, 0, stream>>>(
            h0, W2F + (size_t)e0 * 1048576ull, b2 + (size_t)e0 * 1024, h1, 8192ull * 1024ull,
            nullptr, nullptr, 0);
        gemm_kernel<2><<<dim3(8, 64, g), 256, 0, stream>>>(
            h1, W2F + (size_t)e0 * 1048576ull, b2 + (size_t)e0 * 1024, h0, 8192ull * 1024ull,
            Wo, f, e0);
    }
    final_kernel<<<2048, 256, 0, stream>>>(x, Wg1, bg1, Wg2, bg2, f, bo, out);
}

// Round 2
// 1103.094 us; speedup vs baseline: 1.1807x; 1.0341x over previous
//
#include <hip/hip_runtime.h>
#include <hip/hip_bf16.h>
#include <cstdint>
#include <cstddef>

// MultiGateMixExperts: fp16 MFMA GEMMs, frag-major layout.
// Frag-major layout: frag(tile16 t, kchunk32 c) = 1KB at ((t*32+c)*64+lane)*16B;
// lane l holds M[row=t*16+(l&15)][k=c*32+(l>>4)*8 .. +7] (fp16).
// R7: 256x256 8-phase schedule (T3+T4+T5 from the HK-derived template):
//  - 8 waves (2M x 4N), wave tile 128x64, BK=64 (2 frag kchunks per K-tile),
//    LDS 2 x 64KB double buffer, frag reads stay lane-linear (conflict-free,
//    no swizzle needed -> T2 satisfied by layout).
//  - per K-tile: 4 phases {ds_read subtile; stage 1 half-tile (2 gload_lds);
//    barrier; lgkmcnt(0); setprio(1); 16 MFMA; setprio(0); barrier}.
//  - ONE s_waitcnt vmcnt(6) per tile (phase 4): 3 half-tiles always in flight,
//    never drained in the loop. Stage targets follow region-death order:
//    H0(A-top) dies after P1, H3(B-hi) after P2, H1(A-bot) after P3,
//    H2(B-lo) after P4 => stage H2(t+1)@P1 (other buf), H0/H3/H1(t+2)@P2/3/4
//    (same buf, into dead regions). Ledger: at P4(t)'s vmcnt(6), exactly
//    tile t+1 is complete and {H0,H3,H1}(t+2) are in flight.
//  - all global loads kept OUT of the K-loop (exact vmcnt ledger); vmcnt(0)
//    drain before the LDS-reuse epilogue (also prevents retired-block LDS
//    writes from clamped tail stages).
// Accumulation order per acc element identical to R6 -> same numerics.
// h1 = sigmoid(x@W1[e]+b1); h2 = relu(h1@W2[e]+b2);
// f = (h2@W2[e]+b2).Wo[e] fused into stage-3 epilogue (atomicAdd over n-blocks)
// out_i = softmax(x@Wg_i+bg_i) . (f+bo)

using half8   = __attribute__((ext_vector_type(8))) _Float16;
using floatx4 = __attribute__((ext_vector_type(4))) float;

#define MFMA_QUAD(I0, J0, BR)                                                  \
    _Pragma("unroll")                                                          \
    for (int k = 0; k < 4; ++k) {                                              \
        _Pragma("unroll")                                                      \
        for (int l = 0; l < 2; ++l) {                                          \
            acc[(I0)+k][(J0)+l] = __builtin_amdgcn_mfma_f32_16x16x32_f16(      \
                aR[k][0], BR[l][0], acc[(I0)+k][(J0)+l], 0, 0, 0);             \
            acc[(I0)+k][(J0)+l] = __builtin_amdgcn_mfma_f32_16x16x32_f16(      \
                aR[k][1], BR[l][1], acc[(I0)+k][(J0)+l], 0, 0, 0);             \
        }                                                                      \
    }

// ---------------------------------------------------------------- GEMM ------
// ACT: 0=sigmoid, 1=relu (writes C in frag layout), 2=f-fused (no C store).
template<int ACT>
__global__ __launch_bounds__(512, 2)
void gemm_kernel(const _Float16* __restrict__ A, const _Float16* __restrict__ Bt,
                 const float* __restrict__ bias, _Float16* __restrict__ C,
                 size_t a_estride,
                 const float* __restrict__ Wo, float* __restrict__ f, int e0)
{
    // 2 x 64KB K-tile buffers: halves [0,16384) = A frags (mt*2+kci),
    // [16384,32768) = B frags (nt*2+kci). Lane-linear 1KB frags.
    __shared__ __align__(16) _Float16 sbuf[2][32768];

    const int tid  = threadIdx.x;
    const int lane = tid & 63;
    const int w    = tid >> 6;      // wave 0..7
    const int wm   = w & 1;
    const int wn   = w >> 1;        // 0..3

    // --- XCD-aware windowed remap (gridDim = {8, 16*g}) ---
    // window = 4 m-blocks x 4 n-blocks per XCD: A-window 2MB + B 2MB ~ L2.
    const int flat = blockIdx.x + (blockIdx.y << 3);
    const int xcd  = flat & 7;
    int s = flat >> 3;
    const int g = gridDim.y >> 4;
    int le, mb_base;
    if (g <= 8) {
        const int p = 8 / g;            // XCDs per expert
        le = xcd / p;
        mb_base = (xcd % p) * (32 / p);
    } else {                            // g == 16
        le = (xcd << 1) | (s >> 7);
        s &= 127;
        mb_base = 0;
    }
    const int nb = (s >> 2) & 3;
    const int mb = mb_base + (s >> 4) * 4 + (s & 3);
    const int m0 = mb * 256;
    const int n0 = nb * 256;

    const _Float16* Ae = A    + (size_t)le * a_estride;
    const _Float16* Be = Bt   + (size_t)le * (1024ull * 1024ull);
    const float*    be = bias + (size_t)le * 1024ull;
    _Float16*       Ce = C    + (size_t)le * (8192ull * 1024ull);

    const int mtb_blk = m0 >> 4;        // block's first A m-tile (16 total)
    const int ntb_blk = n0 >> 4;        // block's first B n-tile (16 total)

    // stage sources (per wave, per-lane): wave w owns A m-tiles {w, 8+w} and
    // B n-tiles {w, 8+w}; per tile t the 2 frags (kc=2t,2t+1) are contiguous.
    const _Float16* gA0 = Ae + (size_t)(mtb_blk + w)     * (32 * 512) + lane * 8;
    const _Float16* gA1 = Ae + (size_t)(mtb_blk + 8 + w) * (32 * 512) + lane * 8;
    const _Float16* gB2 = Be + (size_t)(ntb_blk + w)     * (32 * 512) + lane * 8;
    const _Float16* gB3 = Be + (size_t)(ntb_blk + 8 + w) * (32 * 512) + lane * 8;
    // LDS dst offsets (halves), wave-uniform
    const int dA0 = w * 1024;
    const int dA1 = (8 + w) * 1024;
    const int dB2 = 16384 + w * 1024;
    const int dB3 = 16384 + (8 + w) * 1024;

    auto STAGE = [&](const _Float16* gbase, int t, _Float16* bufbase, int dst) {
        const _Float16* src = gbase + (size_t)t * 1024;
        _Float16* d = bufbase + dst;
        __builtin_amdgcn_global_load_lds(
            (const __attribute__((address_space(1))) void*)src,
            (__attribute__((address_space(3))) void*)d, 16, 0, 0);
        __builtin_amdgcn_global_load_lds(
            (const __attribute__((address_space(1))) void*)(src + 512),
            (__attribute__((address_space(3))) void*)(d + 512), 16, 0, 0);
    };

    floatx4 acc[8][4];
#pragma unroll
    for (int i = 0; i < 8; ++i)
#pragma unroll
        for (int j = 0; j < 4; ++j) { floatx4 z = {0.f, 0.f, 0.f, 0.f}; acc[i][j] = z; }

    // ---- prologue: tile0 fully (8 loads), then H0,H3,H1 of tile1 (6 loads)
    STAGE(gA0, 0, &sbuf[0][0], dA0);
    STAGE(gB3, 0, &sbuf[0][0], dB3);
    STAGE(gA1, 0, &sbuf[0][0], dA1);
    STAGE(gB2, 0, &sbuf[0][0], dB2);
    asm volatile("" ::: "memory");      // keep tile0's 8 loads oldest
    STAGE(gA0, 1, &sbuf[1][0], dA0);
    STAGE(gB3, 1, &sbuf[1][0], dB3);
    STAGE(gA1, 1, &sbuf[1][0], dA1);
    asm volatile("s_waitcnt vmcnt(6)" ::: "memory");   // tile0 complete
    __builtin_amdgcn_s_barrier();

    // ---- main loop: 16 K-tiles (K=1024, BK=64), 4 phases each
#pragma unroll 2
    for (int t = 0; t < 16; ++t) {
        _Float16* bc = &sbuf[t & 1][0];
        _Float16* bn = &sbuf[(t & 1) ^ 1][0];
        const int tp1 = (t + 1) & 15;   // wrap-clamped tail stages (harmless)
        const int tp2 = (t + 2) & 15;

        half8 aR[4][2], bR0[2][2], bR1[2][2];

        // -- P1: read A-mh0 (8) + B-nh0 (4); stage H2(t+1) -> other buf
#pragma unroll
        for (int k = 0; k < 4; ++k) {
            const int mtl = ((k >> 1) << 2) + wm * 2 + (k & 1);
            aR[k][0] = *(const half8*)(bc + (mtl * 2 + 0) * 512 + lane * 8);
            aR[k][1] = *(const half8*)(bc + (mtl * 2 + 1) * 512 + lane * 8);
        }
#pragma unroll
        for (int l = 0; l < 2; ++l) {
            const int ntl = wn * 2 + l;
            bR0[l][0] = *(const half8*)(bc + 16384 + (ntl * 2 + 0) * 512 + lane * 8);
            bR0[l][1] = *(const half8*)(bc + 16384 + (ntl * 2 + 1) * 512 + lane * 8);
        }
        STAGE(gB2, tp1, bn, dB2);
        __builtin_amdgcn_s_barrier();
        asm volatile("s_waitcnt lgkmcnt(0)" ::: "memory");
        __builtin_amdgcn_s_setprio(1);
        MFMA_QUAD(0, 0, bR0)
        __builtin_amdgcn_s_setprio(0);
        __builtin_amdgcn_s_barrier();

        // -- P2: read B-nh1 (4); stage H0(t+2) -> this buf (dead region)
#pragma unroll
        for (int l = 0; l < 2; ++l) {
            const int ntl = 8 + wn * 2 + l;
            bR1[l][0] = *(const half8*)(bc + 16384 + (ntl * 2 + 0) * 512 + lane * 8);
            bR1[l][1] = *(const half8*)(bc + 16384 + (ntl * 2 + 1) * 512 + lane * 8);
        }
        STAGE(gA0, tp2, bc, dA0);
        __builtin_amdgcn_s_barrier();
        asm volatile("s_waitcnt lgkmcnt(0)" ::: "memory");
        __builtin_amdgcn_s_setprio(1);
        MFMA_QUAD(0, 2, bR1)
        __builtin_amdgcn_s_setprio(0);
        __builtin_amdgcn_s_barrier();

        // -- P3: read A-mh1 (8); stage H3(t+2)
#pragma unroll
        for (int k = 0; k < 4; ++k) {
            const int mtl = 8 + ((k >> 1) << 2) + wm * 2 + (k & 1);
            aR[k][0] = *(const half8*)(bc + (mtl * 2 + 0) * 512 + lane * 8);
            aR[k][1] = *(const half8*)(bc + (mtl * 2 + 1) * 512 + lane * 8);
        }
        STAGE(gB3, tp2, bc, dB3);
        __builtin_amdgcn_s_barrier();
        asm volatile("s_waitcnt lgkmcnt(0)" ::: "memory");
        __builtin_amdgcn_s_setprio(1);
        MFMA_QUAD(4, 2, bR1)
        __builtin_amdgcn_s_setprio(0);
        __builtin_amdgcn_s_barrier();

        // -- P4: no reads (regs held); stage H1(t+2); per-tile vmcnt gate
        STAGE(gA1, tp2, bc, dA1);
        __builtin_amdgcn_s_barrier();
        __builtin_amdgcn_s_setprio(1);
        MFMA_QUAD(4, 0, bR0)
        __builtin_amdgcn_s_setprio(0);
        asm volatile("s_waitcnt vmcnt(6)" ::: "memory");  // tile t+1 complete
        __builtin_amdgcn_s_barrier();
    }

    // drain in-flight clamped stages before LDS reuse / exit
    asm volatile("s_waitcnt vmcnt(0)" ::: "memory");
    __builtin_amdgcn_s_barrier();

    // ----- epilogue; C/D layout: col=lane&15, row=(lane>>4)*4+r -----
    const int q   = lane >> 4;
    const int l15 = lane & 15;
    float bj[4];
#pragma unroll
    for (int j = 0; j < 4; ++j) {
        const int ntl = ((j >> 1) << 3) + wn * 2 + (j & 1);
        bj[j] = be[n0 + ntl * 16 + l15];
    }

    if (ACT == 2) {
        // f[m, e0+le] += sum_n (acc + b2[n]) * Wo[e0+le, n]
        const float* we = Wo + (size_t)(e0 + le) * 1024;
        float wj[4];
#pragma unroll
        for (int j = 0; j < 4; ++j) {
            const int ntl = ((j >> 1) << 3) + wn * 2 + (j & 1);
            wj[j] = we[n0 + ntl * 16 + l15];
        }
#pragma unroll
        for (int i = 0; i < 8; ++i) {
            const int mtl = ((i >> 1) << 2) + wm * 2 + (i & 1);
            const int mbase = m0 + mtl * 16 + q * 4;
#pragma unroll
            for (int r = 0; r < 4; ++r) {
                float sacc = 0.f;
#pragma unroll
                for (int j = 0; j < 4; ++j) sacc += (acc[i][j][r] + bj[j]) * wj[j];
#pragma unroll
                for (int m = 1; m < 16; m <<= 1) sacc += __shfl_xor(sacc, m, 64);
                if (l15 == 0) atomicAdd(&f[(size_t)(mbase + r) * 16 + (e0 + le)], sacc);
            }
        }
    } else {
        // per-wave repack (private 640-half region of sbuf; no barriers)
        _Float16* T = &sbuf[0][0] + w * 1024;
        const int kcb = n0 >> 5;
#pragma unroll
        for (int i = 0; i < 8; ++i) {
            const int mtl = ((i >> 1) << 2) + wm * 2 + (i & 1);
            const int mtg = mtb_blk + mtl;
#pragma unroll
            for (int jp = 0; jp < 2; ++jp) {
#pragma unroll
                for (int j2 = 0; j2 < 2; ++j2) {
                    const int j = jp * 2 + j2;
#pragma unroll
                    for (int r = 0; r < 4; ++r) {
                        float v = acc[i][j][r] + bj[j];
                        if (ACT == 0) v = 1.0f / (1.0f + __expf(-v));
                        else          v = fmaxf(v, 0.0f);
                        T[(q * 4 + r) * 40 + j2 * 16 + l15] = (_Float16)v;
                    }
                }
                half8 v8 = *(const half8*)(T + l15 * 40 + q * 8);
                const int kcg = kcb + (jp ? 4 + wn : wn);
                *(half8*)(Ce + ((size_t)mtg * 32 + kcg) * 512 + lane * 8) = v8;
            }
        }
    }
}

// --------------------------------------- cast x to fp16 frag layout ---------
__global__ __launch_bounds__(256)
void castx_kernel(const float* __restrict__ x, _Float16* __restrict__ xb)
{
    __shared__ _Float16 tile[64 * 72];   // [m-local][k-local]
    const int k0 = blockIdx.x * 64;
    const int m0 = blockIdx.y * 64;
    const int tid = threadIdx.x;
    const int col4 = (tid & 15) * 4;
    const int rb   = tid >> 4;           // 0..15
#pragma unroll
    for (int p = 0; p < 4; ++p) {
        const int row = rb + p * 16;
        float4 a = *(const float4*)(x + (size_t)(m0 + row) * 1024 + k0 + col4);
        _Float16* d = tile + row * 72 + col4;
        d[0] = (_Float16)a.x; d[1] = (_Float16)a.y; d[2] = (_Float16)a.z; d[3] = (_Float16)a.w;
    }
    __syncthreads();
    const int lane = tid & 63, w = tid >> 6;
    const int l15 = lane & 15, q = lane >> 4;
#pragma unroll
    for (int ff = 0; ff < 2; ++ff) {
        const int fidx = w * 2 + ff;
        const int mi = fidx >> 1, kci = fidx & 1;
        half8 v = *(const half8*)(tile + (mi * 16 + l15) * 72 + kci * 32 + q * 8);
        const size_t mt = (m0 >> 4) + mi, kc = (k0 >> 5) + kci;
        *(half8*)(xb + (mt * 32 + kc) * 512 + lane * 8) = v;
    }
}

// ------------------- W1/W2 [d][h] fp32 -> frag-major fp16 (n=h, k=d) --------
__global__ __launch_bounds__(256)
void wtr_kernel(const float* __restrict__ W1, const float* __restrict__ W2,
                _Float16* __restrict__ W1F, _Float16* __restrict__ W2F)
{
    __shared__ _Float16 tile[64 * 73];   // [k-local][n-local], pad 73
    const int z = blockIdx.z;
    const float* src = (z < 16) ? (W1 + (size_t)z * 1048576ull) : (W2 + (size_t)(z - 16) * 1048576ull);
    _Float16*    dst = (z < 16) ? (W1F + (size_t)z * 1048576ull) : (W2F + (size_t)(z - 16) * 1048576ull);
    const int n0 = blockIdx.x * 64;
    const int k0 = blockIdx.y * 64;
    const int tid = threadIdx.x;
    const int col = tid & 63;
    const int rb  = tid >> 6;            // 0..3
#pragma unroll
    for (int p = 0; p < 16; ++p) {
        const int row = rb * 16 + p;
        tile[row * 73 + col] = (_Float16)src[(size_t)(k0 + row) * 1024 + n0 + col];
    }
    __syncthreads();
    const int lane = tid & 63, w = tid >> 6;
    const int l15 = lane & 15, q = lane >> 4;
#pragma unroll
    for (int ff = 0; ff < 2; ++ff) {
        const int fidx = w * 2 + ff;
        const int nti = fidx >> 1, kci = fidx & 1;
        half8 v;
#pragma unroll
        for (int jj = 0; jj < 8; ++jj)
            v[jj] = tile[(kci * 32 + q * 8 + jj) * 73 + nti * 16 + l15];
        const size_t nt = (n0 >> 4) + nti, kc = (k0 >> 5) + kci;
        *(half8*)(dst + (nt * 32 + kc) * 512 + lane * 8) = v;
    }
}

// ---------------------------------------------------- zero f ----------------
__global__ __launch_bounds__(256)
void zerof_kernel(float* __restrict__ f)
{
    const size_t i = ((size_t)blockIdx.x * 256 + threadIdx.x) * 4;
    float4 z = {0.f, 0.f, 0.f, 0.f};
    *(float4*)(f + i) = z;
}

// ------------------ gates (fp32, full precision) + softmax + combine --------
// R7: 2 rows per wave + float4 Wg loads + unroll (was latency-bound at 86us,
// 205 GB/s, 12% VALU: scalar dependent Wg loads, 1 row/wave).
__global__ __launch_bounds__(256)
void final_kernel(const float* __restrict__ x,
                  const float* __restrict__ Wg1, const float* __restrict__ bg1,
                  const float* __restrict__ Wg2, const float* __restrict__ bg2,
                  const float* __restrict__ f, const float* __restrict__ bo,
                  float* __restrict__ out)
{
    const int lane = threadIdx.x & 63;
    const int w    = threadIdx.x >> 6;
    const int b    = blockIdx.x * 8 + w * 2;
    const float* xA = x + (size_t)b * 1024;
    const float* xB = xA + 1024;
    float g1A[16], g2A[16], g1B[16], g2B[16];
#pragma unroll
    for (int e = 0; e < 16; ++e) { g1A[e] = 0.f; g2A[e] = 0.f; g1B[e] = 0.f; g2B[e] = 0.f; }
#pragma unroll 2
    for (int t = 0; t < 16; ++t) {
        const int d = t * 64 + lane;
        const float xa = xA[d];
        const float xb2 = xB[d];
        const float4* w1 = (const float4*)(Wg1 + (size_t)d * 16);
        const float4* w2 = (const float4*)(Wg2 + (size_t)d * 16);
#pragma unroll
        for (int q4 = 0; q4 < 4; ++q4) {
            const float4 c1 = w1[q4];
            const float4 c2 = w2[q4];
#pragma unroll
            for (int c = 0; c < 4; ++c) {
                const int e = q4 * 4 + c;
                const float v1 = (c == 0) ? c1.x : (c == 1) ? c1.y : (c == 2) ? c1.z : c1.w;
                const float v2 = (c == 0) ? c2.x : (c == 1) ? c2.y : (c == 2) ? c2.z : c2.w;
                g1A[e] += xa * v1; g1B[e] += xb2 * v1;
                g2A[e] += xa * v2; g2B[e] += xb2 * v2;
            }
        }
    }
#pragma unroll
    for (int e = 0; e < 16; ++e) {
#pragma unroll
        for (int m = 1; m < 64; m <<= 1) {
            g1A[e] += __shfl_xor(g1A[e], m, 64);
            g2A[e] += __shfl_xor(g2A[e], m, 64);
            g1B[e] += __shfl_xor(g1B[e], m, 64);
            g2B[e] += __shfl_xor(g2B[e], m, 64);
        }
    }
    const float* fbA = f + (size_t)b * 16;
    const float* fbB = fbA + 16;
#pragma unroll
    for (int rr = 0; rr < 2; ++rr) {
        const float* gp1 = rr ? g1B : g1A;
        const float* gp2 = rr ? g2B : g2A;
        const float* fb  = rr ? fbB : fbA;
        float a1[16], a2[16], m1 = -1e30f, m2 = -1e30f;
#pragma unroll
        for (int e = 0; e < 16; ++e) {
            a1[e] = gp1[e] + bg1[e]; m1 = fmaxf(m1, a1[e]);
            a2[e] = gp2[e] + bg2[e]; m2 = fmaxf(m2, a2[e]);
        }
        float s1 = 0.f, s2 = 0.f, o1 = 0.f, o2 = 0.f;
#pragma unroll
        for (int e = 0; e < 16; ++e) {
            a1[e] = __expf(a1[e] - m1); s1 += a1[e];
            a2[e] = __expf(a2[e] - m2); s2 += a2[e];
        }
#pragma unroll
        for (int e = 0; e < 16; ++e) {
            const float fe = fb[e] + bo[e];
            o1 += a1[e] * fe; o2 += a2[e] * fe;
        }
        if (lane == 0) { out[b + rr] = o1 / s1; out[8192 + b + rr] = o2 / s2; }
    }
}

// ----------------------------------------------------------------------------
extern "C" void kernel_launch(void* const* d_in, const int* in_sizes, int n_in,
                              void* d_out, int out_size, void* d_ws, size_t ws_size,
                              hipStream_t stream)
{
    const float* x   = (const float*)d_in[0];
    const float* W1  = (const float*)d_in[1];
    const float* b1  = (const float*)d_in[2];
    const float* W2  = (const float*)d_in[3];
    const float* b2  = (const float*)d_in[4];
    const float* Wo  = (const float*)d_in[5];
    const float* bo  = (const float*)d_in[6];
    const float* Wg1 = (const float*)d_in[7];
    const float* bg1 = (const float*)d_in[8];
    const float* Wg2 = (const float*)d_in[9];
    const float* bg2 = (const float*)d_in[10];
    float* out = (float*)d_out;

    char* ws = (char*)d_ws;
    _Float16* xb  = (_Float16*)(ws);                         // 16 MB (frag)
    _Float16* W1F = (_Float16*)(ws + 16777216ull);           // 32 MB (frag)
    _Float16* W2F = (_Float16*)(ws + 50331648ull);           // 32 MB (frag)
    float*    f   = (float*)   (ws + 83886080ull);           // 0.5 MB
    char* hbase = ws + 84410368ull;

    int g = 1;
    const int cands[4] = {16, 8, 4, 2};
    for (int ci = 0; ci < 4; ++ci) {
        const size_t need = 84410368ull + 2ull * cands[ci] * 16777216ull;
        if (need <= ws_size) { g = cands[ci]; break; }
    }
    _Float16* h0 = (_Float16*)hbase;
    _Float16* h1 = (_Float16*)(hbase + (size_t)g * 16777216ull);

    castx_kernel<<<dim3(16, 128), 256, 0, stream>>>(x, xb);
    wtr_kernel<<<dim3(16, 16, 32), 256, 0, stream>>>(W1, W2, W1F, W2F);
    zerof_kernel<<<128, 256, 0, stream>>>(f);

    for (int e0 = 0; e0 < 16; e0 += g) {
        gemm_kernel<0><<<dim3(8, 16 * g), 512, 0, stream>>>(
            xb, W1F + (size_t)e0 * 1048576ull, b1 + (size_t)e0 * 1024, h0, 0,
            nullptr, nullptr, 0);
        gemm_kernel<1><<<dim3(8, 16 * g), 512, 0, stream>>>(
            h0, W2F + (size_t)e0 * 1048576ull, b2 + (size_t)e0 * 1024, h1, 8192ull * 1024ull,
            nullptr, nullptr, 0);
        gemm_kernel<2><<<dim3(8, 16 * g), 512, 0, stream>>>(
            h1, W2F + (size_t)e0 * 1048576ull, b2 + (size_t)e0 * 1024, h0, 8192ull * 1024ull,
            Wo, f, e0);
    }
    final_kernel<<<1024, 256, 0, stream>>>(x, Wg1, bg1, Wg2, bg2, f, bo, out);
}